// Round 1
// baseline (63.354 us; speedup 1.0000x reference)
//
#include <hip/hip_runtime.h>

// StereoMatching: out[b,h,w] = left[b,h,w] * sum_{d=0..191, d<=w} d * right[b,h,w-d]
// B=2, C=1, H=384, W=1248, DISP=192. Rows are independent: 768 rows of 1248.
//
// Window decomposition: S[w] = w*A[w] - B[w], A = sum r[j], B = sum j*r[j],
// window j in [w-191, w] (zero-padded below 0). Each thread computes the
// initial window once, then slides it across KOUT=5 consecutive outputs.

#define WID 1248
#define DISP 192
#define KOUT 5
#define THREADS 256
#define NROWS 768  // B*H = 2*384

__global__ __launch_bounds__(THREADS) void stereo_row_kernel(
    const float* __restrict__ left,
    const float* __restrict__ right,
    float* __restrict__ out)
{
    // [0, DISP)           : zero left pad (handles j < 0)
    // [DISP, DISP+WID)    : right row
    // [DISP+WID, +8)      : zero right pad (handles w up to WID+1 reads)
    __shared__ float r_pad[DISP + WID + 8];

    const int row = blockIdx.x;            // b*H + h
    const long base = (long)row * WID;
    const int tid = threadIdx.x;

    for (int i = tid; i < DISP; i += THREADS) r_pad[i] = 0.0f;
    if (tid < 8) r_pad[DISP + WID + tid] = 0.0f;
    for (int i = tid; i < WID; i += THREADS) r_pad[DISP + i] = right[base + i];
    __syncthreads();

    const int w0 = tid * KOUT;
    if (w0 >= WID) return;                 // threads 250..255 idle

    // Initial window for output w0: j in [w0-191, w0]
    float A = 0.0f, Bs = 0.0f;
    const int jstart = w0 - (DISP - 1);
    #pragma unroll 4
    for (int i = 0; i < DISP; ++i) {
        float rj = r_pad[DISP + jstart + i];   // zero for j < 0
        float jf = (float)(jstart + i);
        A += rj;
        Bs = fmaf(jf, rj, Bs);
    }

    {
        float S = fmaf((float)w0, A, -Bs);
        out[base + w0] = left[base + w0] * S;
    }

    #pragma unroll
    for (int k = 1; k < KOUT; ++k) {
        const int w = w0 + k;
        float rn = r_pad[DISP + w];        // new j = w   (right pad covers w >= WID)
        float ro = r_pad[w];               // old j = w - DISP, pad index DISP + (w-DISP)
        A += rn - ro;
        Bs += (float)w * rn - (float)(w - DISP) * ro;
        if (w < WID) {
            float S = fmaf((float)w, A, -Bs);
            out[base + w] = left[base + w] * S;
        }
    }
}

extern "C" void kernel_launch(void* const* d_in, const int* in_sizes, int n_in,
                              void* d_out, int out_size, void* d_ws, size_t ws_size,
                              hipStream_t stream) {
    const float* left  = (const float*)d_in[0];
    const float* right = (const float*)d_in[1];
    float* out = (float*)d_out;
    stereo_row_kernel<<<dim3(NROWS), dim3(THREADS), 0, stream>>>(left, right, out);
}

// Round 2
// 61.907 us; speedup vs baseline: 1.0234x; 1.0234x over previous
//
#include <hip/hip_runtime.h>

// StereoMatching: out[b,h,w] = left[b,h,w] * sum_{d=0..191, d<=w} d * right[b,h,w-d]
// B=2, C=1, H=384, W=1248, DISP=192.
//
// Scan formulation: for a segment starting at wstart, define
//   arr[i] = right[wstart-191+i] (zero outside [0,WID)), i in [0,504)
//   Ps[i]  = sum_{k<i} arr[k],  Qs[i] = sum_{k<i} k*arr[k]   (exclusive)
// Output t (w = wstart+t):  window is arr[t .. t+191], and
//   S = (t+191)*(Ps[t+192]-Ps[t]) - (Qs[t+192]-Qs[t])
// verified algebraically and on a DISP=2 toy case.

#define WID 1248
#define DISP 192
#define SEG 312          // 4 segments per row, 4*312 = 1248
#define THREADS 256
#define NROWS 768        // B*H

__global__ __launch_bounds__(THREADS) void stereo_scan_kernel(
    const float* __restrict__ left,
    const float* __restrict__ right,
    float* __restrict__ out)
{
    __shared__ float Ps[520];
    __shared__ float Qs[520];
    __shared__ float wsS[4], wsQ[4];

    const int bid = blockIdx.x;
    const int row = bid >> 2;          // b*H + h
    const int seg = bid & 3;
    const int wstart = seg * SEG;
    const long base = (long)row * WID;
    const int tid = threadIdx.x;
    const int lane = tid & 63;
    const int wv = tid >> 6;

    // Each thread owns elements i0, i0+1 of arr (504 real, rest zero).
    const int i0 = 2 * tid;
    const int j0 = wstart - (DISP - 1) + i0;   // global right index of arr[i0]
    float e0 = (j0     >= 0 && j0     < WID) ? right[base + j0]     : 0.0f;
    float e1 = (j0 + 1 >= 0 && j0 + 1 < WID) ? right[base + j0 + 1] : 0.0f;

    float s = e0 + e1;
    float q = fmaf((float)i0, e0, (float)(i0 + 1) * e1);
    const float ls = s, lq = q;

    // Inclusive wave scan (64 lanes) of the (s,q) pair.
    #pragma unroll
    for (int d = 1; d < 64; d <<= 1) {
        float ts = __shfl_up(s, (unsigned)d, 64);
        float tq = __shfl_up(q, (unsigned)d, 64);
        if (lane >= d) { s += ts; q += tq; }
    }
    if (lane == 63) { wsS[wv] = s; wsQ[wv] = q; }
    __syncthreads();

    float offS = 0.0f, offQ = 0.0f;
    if (wv > 0) { offS += wsS[0]; offQ += wsQ[0]; }
    if (wv > 1) { offS += wsS[1]; offQ += wsQ[1]; }
    if (wv > 2) { offS += wsS[2]; offQ += wsQ[2]; }

    const float exS = offS + s - ls;   // exclusive prefix before arr[i0]
    const float exQ = offQ + q - lq;
    Ps[i0]     = exS;
    Ps[i0 + 1] = exS + e0;
    Qs[i0]     = exQ;
    Qs[i0 + 1] = fmaf((float)i0, e0, exQ);
    __syncthreads();

    // Outputs: t = tid and t = 256+tid (for tid < 56). Stride-1 LDS reads.
    {
        const int t = tid;
        const float A  = Ps[t + DISP] - Ps[t];
        const float Qw = Qs[t + DISP] - Qs[t];
        const float S  = fmaf((float)(t + DISP - 1), A, -Qw);
        const int w = wstart + t;
        out[base + w] = left[base + w] * S;
    }
    if (tid < SEG - THREADS) {
        const int t = THREADS + tid;
        const float A  = Ps[t + DISP] - Ps[t];
        const float Qw = Qs[t + DISP] - Qs[t];
        const float S  = fmaf((float)(t + DISP - 1), A, -Qw);
        const int w = wstart + t;
        out[base + w] = left[base + w] * S;
    }
}

extern "C" void kernel_launch(void* const* d_in, const int* in_sizes, int n_in,
                              void* d_out, int out_size, void* d_ws, size_t ws_size,
                              hipStream_t stream) {
    const float* left  = (const float*)d_in[0];
    const float* right = (const float*)d_in[1];
    float* out = (float*)d_out;
    stereo_scan_kernel<<<dim3(NROWS * 4), dim3(THREADS), 0, stream>>>(left, right, out);
}